// Round 1
// baseline (793.073 us; speedup 1.0000x reference)
//
#include <hip/hip_runtime.h>

#define HID 128
#define SEQ 1024
#define NTHREADS 512

// Quad (4-lane) all-reduce add via DPP quad_perm. Lanes 4j..4j+3 all end with
// the sum of their 4 values (bitwise-identical across lanes: commutative tree).
__device__ __forceinline__ float quad_reduce_add(float x) {
  union { float f; int i; } u, v;
  u.f = x;
  v.i = __builtin_amdgcn_update_dpp(0, u.i, 0xB1, 0xF, 0xF, true); // quad_perm(1,0,3,2)
  u.f += v.f;
  v.i = __builtin_amdgcn_update_dpp(0, u.i, 0x4E, 0xF, 0xF, true); // quad_perm(2,3,0,1)
  u.f += v.f;
  return u.f;
}

__device__ __forceinline__ float sigmoidf_(float x) {
  x = fminf(fmaxf(x, -30.f), 30.f);
  float e = __expf(-x);
  return __builtin_amdgcn_rcpf(1.f + e);
}

__device__ __forceinline__ float tanhf_(float x) {
  x = fminf(fmaxf(x, -15.f), 15.f);
  float e = __expf(-2.f * x);
  return (1.f - e) * __builtin_amdgcn_rcpf(1.f + e);
}

__global__ __launch_bounds__(NTHREADS, 2)
void gru_kernel(const float* __restrict__ x,     // [B, S, 1]
                const float* __restrict__ w_ih,  // [3H, 1]
                const float* __restrict__ w_hh,  // [3H, H]
                const float* __restrict__ b_ih,  // [3H]
                const float* __restrict__ b_hh,  // [3H]
                const float* __restrict__ w_fc,  // [1, H]
                const float* __restrict__ b_fc,  // [1]
                float* __restrict__ out)         // [B, 1]
{
  __shared__ float xs[SEQ];
  __shared__ float hbuf[2][HID];
  __shared__ float red[8];

  const int t = threadIdx.x;
  const int b = blockIdx.x;
  const int j = t >> 2;   // hidden unit
  const int q = t & 3;    // k-quarter

  // stage x[b, :] into LDS (coalesced)
  const float* xrow = x + (size_t)b * SEQ;
  for (int i = t; i < SEQ; i += NTHREADS) xs[i] = xrow[i];
  if (t < HID) hbuf[0][t] = 0.f;

  // W_hh slices for rows j (r), H+j (z), 2H+j (n), cols [q*32, q*32+32)
  float4 wr[8], wz[8], wn[8];
  {
    const float4* pr = (const float4*)(w_hh + (size_t)j * HID + q * 32);
    const float4* pz = (const float4*)(w_hh + (size_t)(HID + j) * HID + q * 32);
    const float4* pn = (const float4*)(w_hh + (size_t)(2 * HID + j) * HID + q * 32);
#pragma unroll
    for (int k = 0; k < 8; ++k) { wr[k] = pr[k]; wz[k] = pz[k]; wn[k] = pn[k]; }
  }
  const float bhr = b_hh[j], bhz = b_hh[HID + j], bhn = b_hh[2 * HID + j];
  const float wir = w_ih[j], wiz = w_ih[HID + j], win = w_ih[2 * HID + j];
  const float bir = b_ih[j], biz = b_ih[HID + j], bin = b_ih[2 * HID + j];

  float hprev = 0.f;
  int cur = 0;
  __syncthreads();

  for (int s = 0; s < SEQ; ++s) {
    const float xt = xs[s];
    const float4* hp = (const float4*)(hbuf[cur]) + q * 8;
    float4 ar = make_float4(0.f, 0.f, 0.f, 0.f);
    float4 az = make_float4(0.f, 0.f, 0.f, 0.f);
    float4 an = make_float4(0.f, 0.f, 0.f, 0.f);
#pragma unroll
    for (int k = 0; k < 8; ++k) {
      float4 hv = hp[k];
      ar.x = fmaf(wr[k].x, hv.x, ar.x);
      ar.y = fmaf(wr[k].y, hv.y, ar.y);
      ar.z = fmaf(wr[k].z, hv.z, ar.z);
      ar.w = fmaf(wr[k].w, hv.w, ar.w);
      az.x = fmaf(wz[k].x, hv.x, az.x);
      az.y = fmaf(wz[k].y, hv.y, az.y);
      az.z = fmaf(wz[k].z, hv.z, az.z);
      az.w = fmaf(wz[k].w, hv.w, az.w);
      an.x = fmaf(wn[k].x, hv.x, an.x);
      an.y = fmaf(wn[k].y, hv.y, an.y);
      an.z = fmaf(wn[k].z, hv.z, an.z);
      an.w = fmaf(wn[k].w, hv.w, an.w);
    }
    float dr = (ar.x + ar.y) + (ar.z + ar.w);
    float dz = (az.x + az.y) + (az.z + az.w);
    float dn = (an.x + an.y) + (an.z + an.w);
    dr = quad_reduce_add(dr);
    dz = quad_reduce_add(dz);
    dn = quad_reduce_add(dn);

    const float r = sigmoidf_(fmaf(xt, wir, bir) + dr + bhr);
    const float z = sigmoidf_(fmaf(xt, wiz, biz) + dz + bhz);
    const float n = tanhf_(fmaf(xt, win, bin) + r * (dn + bhn));
    const float hnew = n + z * (hprev - n);
    hprev = hnew;
    if (q == 0) hbuf[cur ^ 1][j] = hnew;
    cur ^= 1;
    __syncthreads();
  }

  // epilogue: out[b] = relu(h_T) . w_fc + b_fc
  float v = (q == 0) ? fmaxf(hprev, 0.f) * w_fc[j] : 0.f;
#pragma unroll
  for (int off = 1; off < 64; off <<= 1) v += __shfl_xor(v, off);
  if ((t & 63) == 0) red[t >> 6] = v;
  __syncthreads();
  if (t == 0) {
    float sum = 0.f;
#pragma unroll
    for (int w = 0; w < 8; ++w) sum += red[w];
    out[b] = sum + b_fc[0];
  }
}

extern "C" void kernel_launch(void* const* d_in, const int* in_sizes, int n_in,
                              void* d_out, int out_size, void* d_ws, size_t ws_size,
                              hipStream_t stream) {
  const float* x    = (const float*)d_in[0];
  const float* w_ih = (const float*)d_in[1];
  const float* w_hh = (const float*)d_in[2];
  const float* b_ih = (const float*)d_in[3];
  const float* b_hh = (const float*)d_in[4];
  const float* w_fc = (const float*)d_in[5];
  const float* b_fc = (const float*)d_in[6];
  gru_kernel<<<256, NTHREADS, 0, stream>>>(x, w_ih, w_hh, b_ih, b_hh, w_fc, b_fc,
                                           (float*)d_out);
}